// Round 7
// baseline (369.040 us; speedup 1.0000x reference)
//
#include <hip/hip_runtime.h>
#include <math.h>

#define NB 16
#define NCH 64
#define NPTS 4096
#define NM 257
#define NKF 128
#define NTEMB 256
#define NHID 128

#define MT 32          // m-tile
#define NMT 9          // ceil(257/32)
#define NCHUNK 64      // n-chunk

#define INV_PI 0.31830988618379067154f

// ---- workspace layout (float offsets) ----
#define OFF_KAPPA 0
#define OFF_OMEGA 320
#define OFF_BAND  640
#define OFF_GATE  960              // NB*NM = 4112 -> reserve 4160
#define OFF_TCOND 5120             // NB*NCH = 1024
#define OFF_YR    6144
#define BMC       263168           // NB*NM*NCH
#define OFF_YI    (OFF_YR + BMC)
#define OFF_PART  (OFF_YI + BMC)   // NS*BMC (real) then NS*BMC (imag)

__device__ __forceinline__ float sigf(float x){ return 1.0f/(1.0f+expf(-x)); }
__device__ __forceinline__ float softplusf(float x){ return (x>20.0f)? x : log1pf(expf(x)); }

// ---------------------------------------------------------------- prep_freq
__global__ void k_prep_freq(const float* __restrict__ kraw,
                            const float* __restrict__ gom,
                            const float* __restrict__ glow,
                            const float* __restrict__ gmid,
                            const float* __restrict__ ghigh,
                            float* __restrict__ ws){
  __shared__ float kpos[NKF];
  __shared__ float th_s[2];
  const int t = threadIdx.x;
  if(t==0){
    float acc = 0.0f;
    for(int k=0;k<NKF;k++){ acc += softplusf(kraw[k]); kpos[k]=acc; }
    // sorted |kappa| = [0, kpos[0],kpos[0], kpos[1],kpos[1], ...]
    // q=0.4: pos=102.4 -> a[102]=kpos[50], a[103]=kpos[51]
    // q=0.8: pos=204.8 -> a[204]=kpos[101], a[205]=kpos[102]
    th_s[0] = 0.6f*kpos[50]  + 0.4f*kpos[51];
    th_s[1] = 0.2f*kpos[101] + 0.8f*kpos[102];
  }
  __syncthreads();
  const float th1 = th_s[0], th2 = th_s[1];
  const float gl = sigf(glow[0]), gm = sigf(gmid[0]), gh = sigf(ghigh[0]);
  for(int m=t; m<NM; m+=blockDim.x){
    float kap = (m<NKF) ? -kpos[NKF-1-m] : ((m==NKF) ? 0.0f : kpos[m-NKF-1]);
    float ka = fabsf(kap);
    float band = (ka<=th1) ? gl : ((ka<=th2) ? gm : gh);
    float om = fmaxf(softplusf(gom[m]), 1e-6f);
    ws[OFF_KAPPA+m] = kap;
    ws[OFF_BAND +m] = band;
    ws[OFF_OMEGA+m] = om;
  }
}

// ---------------------------------------------------------------- prep_batch
__global__ void k_prep_batch(const float* __restrict__ temb,
                             const float* __restrict__ w1, const float* __restrict__ b1,
                             const float* __restrict__ w2, const float* __restrict__ b2,
                             const float* __restrict__ tprojw, const float* __restrict__ tprojb,
                             const float* __restrict__ tau0p, const float* __restrict__ tau1p,
                             const float* __restrict__ alphap,
                             float* __restrict__ ws){
  const int b = blockIdx.x;
  const int t = threadIdx.x;
  __shared__ float te[NTEMB], ste[NTEMB], hid[NHID], red[64];
  __shared__ float tau_sh;
  {
    float v = temb[(size_t)b*NTEMB + t];   // blockDim == NTEMB == 256
    te[t] = v;
    ste[t] = v * sigf(v);
  }
  __syncthreads();
  if(t<NHID){
    float acc = b1[t];
    const float* wrow = w1 + (size_t)t*NTEMB;
    for(int k=0;k<NTEMB;k++) acc = fmaf(te[k], wrow[k], acc);
    hid[t] = acc * sigf(acc);
  }
  __syncthreads();
  if(t<64) red[t] = hid[t]*w2[t] + hid[t+64]*w2[t+64];
  __syncthreads();
  if(t==0){
    float s = 0.0f;
    for(int i=0;i<64;i++) s += red[i];
    float st = tanhf(s + b2[0]);
    tau_sh = tau0p[0] + softplusf(tau1p[0])*st;
  }
  __syncthreads();
  const float alpha = softplusf(alphap[0]) + 1e-12f;
  const float tau = tau_sh;
  for(int m=t; m<NM; m+=256){
    float ka = fabsf(ws[OFF_KAPPA+m]);
    ws[OFF_GATE + b*NM + m] = ws[OFF_BAND+m] * sigf(alpha*(tau-ka));
  }
  if(t<NCH){
    float acc = tprojb[t];
    const float* wrow = tprojw + (size_t)t*NTEMB;
    for(int k=0;k<NTEMB;k++) acc = fmaf(ste[k], wrow[k], acc);
    ws[OFF_TCOND + b*NCH + t] = acc;
  }
}

// ---------------------------------------------------------------- analysis
// grid (NMT, NS, NB); block 256.
// Thread owns 2 channels x 4 m. Partial sums over its n-segment to ws.
__global__ __launch_bounds__(256)
void k_analysis(const float* __restrict__ xf, const float* __restrict__ z,
                const float* __restrict__ gaborc,
                float* __restrict__ ws, int nsegLen){
  __shared__ float xs[NCH][68];            // [c][n] padded: +68 keeps b128 align + spreads banks
  __shared__ float cws[NCHUNK][MT];        // [n][m]
  __shared__ float sws[NCHUNK][MT];
  __shared__ float zs[NCHUNK];
  __shared__ float kap_s[MT], gc_s[MT], iom_s[MT];

  const int t = threadIdx.x;
  const int b = blockIdx.z, mt = blockIdx.x, ns = blockIdx.y;
  const int m0 = mt*MT;

  if(t<MT){
    int mg = min(m0+t, NM-1);
    kap_s[t] = ws[OFF_KAPPA+mg];
    gc_s[t]  = gaborc[mg];
    iom_s[t] = 1.0f/ws[OFF_OMEGA+mg];
  }

  // staging roles
  const int cst = t>>2;            // 0..63
  const int j0  = (t&3)*4;         // 0,4,8,12
  const float tc = ws[OFF_TCOND + b*NCH + cst];

  // compute roles
  const int mq = t&7;              // m-quad (4 m)
  const int cg = t>>3;             // 0..31 -> 2 channels
  const int c0 = 2*cg;

  float ar0[4]={0,0,0,0}, ai0[4]={0,0,0,0};
  float ar1[4]={0,0,0,0}, ai1[4]={0,0,0,0};

  const int nbase0 = ns*nsegLen;
  const float* xrowBase = xf + ((size_t)b*NCH + cst)*NPTS;

  for(int nb = nbase0; nb < nbase0+nsegLen; nb += NCHUNK){
    __syncthreads();                                   // prev chunk reads done
    if(t<NCHUNK) zs[t] = z[(size_t)b*NPTS + nb + t];
    const float* xrow = xrowBase + nb;
    #pragma unroll
    for(int i=0;i<4;i++){
      float4 v = *(const float4*)(xrow + j0 + 16*i);
      v.x += tc; v.y += tc; v.z += tc; v.w += tc;
      *(float4*)&xs[cst][j0 + 16*i] = v;
    }
    __syncthreads();                                   // zs/xs ready
    {
      const int m = t&31, nn = t>>5;
      const float kap = kap_s[m], gcv = gc_s[m], iom = iom_s[m];
      #pragma unroll
      for(int j=0;j<8;j++){
        int n = nn + 8*j;
        float zv = zs[n];
        float sv, cv;
        sincosf(zv*kap, &sv, &cv);
        float e = fmaf(zv, INV_PI, -gcv)*iom;
        float w = expf(-0.5f*e*e);
        cws[n][m] = cv*w;
        sws[n][m] = sv*w;
      }
    }
    __syncthreads();                                   // basis ready
    #pragma unroll 2
    for(int n=0;n<NCHUNK;n++){
      float x0 = xs[c0  ][n];
      float x1 = xs[c0+1][n];
      float4 c4 = *(const float4*)&cws[n][mq*4];
      float4 s4 = *(const float4*)&sws[n][mq*4];
      float cv4[4]={c4.x,c4.y,c4.z,c4.w};
      float sv4[4]={s4.x,s4.y,s4.z,s4.w};
      #pragma unroll
      for(int q=0;q<4;q++){
        ar0[q] = fmaf(x0, cv4[q], ar0[q]);
        ai0[q] = fmaf(x0, sv4[q], ai0[q]);
        ar1[q] = fmaf(x1, cv4[q], ar1[q]);
        ai1[q] = fmaf(x1, sv4[q], ai1[q]);
      }
    }
  }
  const int NSg = gridDim.y;
  float* pr = ws + OFF_PART + (size_t)(ns*NB + b)*NM*NCH;
  float* pi = pr + (size_t)NSg*BMC;
  #pragma unroll
  for(int q=0;q<4;q++){
    int m = m0 + mq*4 + q;
    if(m < NM){
      pr[(size_t)m*NCH + c0  ] = ar0[q];
      pr[(size_t)m*NCH + c0+1] = ar1[q];
      pi[(size_t)m*NCH + c0  ] = ai0[q];
      pi[(size_t)m*NCH + c0+1] = ai1[q];
    }
  }
}

// ---------------------------------------------------------------- reduce + gate + spectral multiply
__global__ void k_reduce_mult(const float* __restrict__ wr, const float* __restrict__ wi,
                              float* __restrict__ ws, int NS){
  int idx = blockIdx.x*256 + threadIdx.x;
  if(idx >= BMC) return;
  int c = idx & 63;
  int m = (idx >> 6) % NM;
  int b = idx / (NM*NCH);
  const float* part = ws + OFF_PART;
  size_t ph = (size_t)NS*BMC;
  float sr=0.0f, si=0.0f;
  for(int s=0;s<NS;s++){
    size_t o = ((size_t)(s*NB + b)*NM + m)*NCH + c;
    sr += part[o];
    si += part[o+ph];
  }
  float g  = ws[OFF_GATE + b*NM + m] * (1.0f/(float)NPTS);
  float Xr =  g*sr;
  float Xi = -g*si;
  float wrv = wr[(size_t)c*NM+m], wiv = wi[(size_t)c*NM+m];
  ws[OFF_YR + idx] =   Xr*wrv - Xi*wiv;
  ws[OFF_YI + idx] = -(Xr*wiv + Xi*wrv);    // pre-negated: synthesis is pure +FMA
}

// ---------------------------------------------------------------- synthesis
// grid (NPTS/64, NB); block 256. Thread owns 4c x 4n.
__global__ __launch_bounds__(256)
void k_synth(const float* __restrict__ z, const float* __restrict__ gaborc,
             const float* __restrict__ bias, const float* __restrict__ ws,
             float* __restrict__ out){
  __shared__ float yrs[MT][68], yis[MT][68];   // [m][c] padded
  __shared__ float cws[MT][NCHUNK], sws[MT][NCHUNK]; // [m][n]
  __shared__ float zs[NCHUNK];
  __shared__ float kap_s[MT], gc_s[MT], iom_s[MT];

  const int t = threadIdx.x;
  const int b = blockIdx.y;
  const int nb = blockIdx.x*NCHUNK;
  const int ci = t&15, ni = t>>4;

  if(t<NCHUNK) zs[t] = z[(size_t)b*NPTS + nb + t];

  float acc[4][4] = {};

  for(int mcb=0; mcb<NM; mcb+=MT){
    __syncthreads();                                 // prev chunk reads done (also covers zs)
    if(t<MT){
      int mg = min(mcb+t, NM-1);
      kap_s[t] = ws[OFF_KAPPA+mg];
      gc_s[t]  = gaborc[mg];
      iom_s[t] = 1.0f/ws[OFF_OMEGA+mg];
    }
    #pragma unroll
    for(int e=0;e<2;e++){
      int fi = t + e*256;          // 512 float4 slots = 32m x 64c
      int m  = fi >> 4;
      int cc = (fi & 15) << 2;
      float4 vr, vi;
      if(mcb + m < NM){
        size_t o_ = ((size_t)b*NM + (mcb+m))*NCH + cc;
        vr = *(const float4*)(ws + OFF_YR + o_);
        vi = *(const float4*)(ws + OFF_YI + o_);
      } else {
        vr = make_float4(0,0,0,0); vi = vr;          // zero-pad tail m
      }
      *(float4*)&yrs[m][cc] = vr;
      *(float4*)&yis[m][cc] = vi;
    }
    __syncthreads();                                 // kap_s / Y ready
    {
      int n = t&63, mm = t>>6;
      float zv = zs[n], zp = zv*INV_PI;
      #pragma unroll
      for(int j=0;j<8;j++){
        int m = mm + 4*j;
        float sv, cv;
        sincosf(zv*kap_s[m], &sv, &cv);
        float e = (zp - gc_s[m])*iom_s[m];
        float w = expf(-0.5f*e*e);
        cws[m][n] = cv*w;
        sws[m][n] = sv*w;
      }
    }
    __syncthreads();                                 // basis ready
    #pragma unroll 4
    for(int m=0;m<MT;m++){
      float4 yr4 = *(const float4*)&yrs[m][ci<<2];
      float4 yi4 = *(const float4*)&yis[m][ci<<2];
      float4 c4  = *(const float4*)&cws[m][ni<<2];
      float4 s4  = *(const float4*)&sws[m][ni<<2];
      float yrv[4]={yr4.x,yr4.y,yr4.z,yr4.w};
      float yiv[4]={yi4.x,yi4.y,yi4.z,yi4.w};
      float cv4[4]={c4.x,c4.y,c4.z,c4.w};
      float sv4[4]={s4.x,s4.y,s4.z,s4.w};
      #pragma unroll
      for(int a=0;a<4;a++){
        #pragma unroll
        for(int q=0;q<4;q++){
          acc[a][q] = fmaf(yrv[a], cv4[q], acc[a][q]);
          acc[a][q] = fmaf(yiv[a], sv4[q], acc[a][q]);   // yi pre-negated
        }
      }
    }
  }
  #pragma unroll
  for(int a=0;a<4;a++){
    int c = (ci<<2) + a;
    float bv = bias[c];
    float4 v;
    v.x = acc[a][0]+bv; v.y = acc[a][1]+bv; v.z = acc[a][2]+bv; v.w = acc[a][3]+bv;
    *(float4*)(out + ((size_t)b*NCH + c)*NPTS + nb + (ni<<2)) = v;
  }
}

// ---------------------------------------------------------------- launch
extern "C" void kernel_launch(void* const* d_in, const int* in_sizes, int n_in,
                              void* d_out, int out_size, void* d_ws, size_t ws_size,
                              hipStream_t stream){
  const float* x_feat = (const float*)d_in[0];
  const float* z      = (const float*)d_in[1];
  const float* temb   = (const float*)d_in[2];
  const float* kraw   = (const float*)d_in[3];
  const float* gaborc = (const float*)d_in[4];
  const float* gom    = (const float*)d_in[5];
  const float* wr     = (const float*)d_in[6];
  const float* wi     = (const float*)d_in[7];
  const float* bias   = (const float*)d_in[8];
  const float* tprojw = (const float*)d_in[9];
  const float* tprojb = (const float*)d_in[10];
  const float* w1     = (const float*)d_in[11];
  const float* b1     = (const float*)d_in[12];
  const float* w2     = (const float*)d_in[13];
  const float* b2     = (const float*)d_in[14];
  const float* tau0   = (const float*)d_in[15];
  const float* tau1   = (const float*)d_in[16];
  const float* alphar = (const float*)d_in[17];
  const float* glow   = (const float*)d_in[18];
  const float* gmid   = (const float*)d_in[19];
  const float* ghigh  = (const float*)d_in[20];
  float* out = (float*)d_out;
  float* ws  = (float*)d_ws;

  int NS = 4;                                   // n-split for load balance (576 blocks)
  size_t need = (size_t)(OFF_PART + 2*NS*BMC) * sizeof(float);
  if(ws_size < need) NS = 1;                    // fallback: 144 blocks, ~4 MB ws

  k_prep_freq <<<1, 256, 0, stream>>>(kraw, gom, glow, gmid, ghigh, ws);
  k_prep_batch<<<NB, 256, 0, stream>>>(temb, w1, b1, w2, b2, tprojw, tprojb,
                                       tau0, tau1, alphar, ws);
  k_analysis  <<<dim3(NMT, NS, NB), 256, 0, stream>>>(x_feat, z, gaborc, ws, NPTS/NS);
  k_reduce_mult<<<(BMC+255)/256, 256, 0, stream>>>(wr, wi, ws, NS);
  k_synth     <<<dim3(NPTS/NCHUNK, NB), 256, 0, stream>>>(z, gaborc, bias, ws, out);
}

// Round 8
// 318.587 us; speedup vs baseline: 1.1584x; 1.1584x over previous
//
#include <hip/hip_runtime.h>
#include <math.h>

#define NB 16
#define NCH 64
#define NPTS 4096
#define NM 257
#define NKF 128
#define NTEMB 256
#define NHID 128

#define MT 32          // m-tile
#define NMT 9          // ceil(257/32)
#define NCHUNK 64      // n-chunk

#define INV_PI 0.31830988618379067154f

// ---- workspace layout (float offsets) ----
#define OFF_KAPPA 0
#define OFF_OMEGA 320
#define OFF_BAND  640
#define OFF_GATE  960              // NB*NM = 4112 -> reserve 4160
#define OFF_TCOND 5120             // NB*NCH = 1024
#define OFF_YR    6144
#define BMC       263168           // NB*NM*NCH
#define OFF_YI    (OFF_YR + BMC)
#define OFF_PART  (OFF_YI + BMC)   // NS*BMC (real) then NS*BMC (imag)

__device__ __forceinline__ float sigf(float x){ return 1.0f/(1.0f+expf(-x)); }
__device__ __forceinline__ float softplusf(float x){ return (x>20.0f)? x : log1pf(expf(x)); }

// ---------------------------------------------------------------- prep_freq
__global__ void k_prep_freq(const float* __restrict__ kraw,
                            const float* __restrict__ gom,
                            const float* __restrict__ glow,
                            const float* __restrict__ gmid,
                            const float* __restrict__ ghigh,
                            float* __restrict__ ws){
  __shared__ float kpos[NKF];
  __shared__ float th_s[2];
  const int t = threadIdx.x;
  if(t==0){
    float acc = 0.0f;
    for(int k=0;k<NKF;k++){ acc += softplusf(kraw[k]); kpos[k]=acc; }
    // sorted |kappa| = [0, kpos[0],kpos[0], kpos[1],kpos[1], ...]
    // q=0.4: pos=102.4 -> a[102]=kpos[50], a[103]=kpos[51]
    // q=0.8: pos=204.8 -> a[204]=kpos[101], a[205]=kpos[102]
    th_s[0] = 0.6f*kpos[50]  + 0.4f*kpos[51];
    th_s[1] = 0.2f*kpos[101] + 0.8f*kpos[102];
  }
  __syncthreads();
  const float th1 = th_s[0], th2 = th_s[1];
  const float gl = sigf(glow[0]), gm = sigf(gmid[0]), gh = sigf(ghigh[0]);
  for(int m=t; m<NM; m+=blockDim.x){
    float kap = (m<NKF) ? -kpos[NKF-1-m] : ((m==NKF) ? 0.0f : kpos[m-NKF-1]);
    float ka = fabsf(kap);
    float band = (ka<=th1) ? gl : ((ka<=th2) ? gm : gh);
    float om = fmaxf(softplusf(gom[m]), 1e-6f);
    ws[OFF_KAPPA+m] = kap;
    ws[OFF_BAND +m] = band;
    ws[OFF_OMEGA+m] = om;
  }
}

// ---------------------------------------------------------------- prep_batch
__global__ void k_prep_batch(const float* __restrict__ temb,
                             const float* __restrict__ w1, const float* __restrict__ b1,
                             const float* __restrict__ w2, const float* __restrict__ b2,
                             const float* __restrict__ tprojw, const float* __restrict__ tprojb,
                             const float* __restrict__ tau0p, const float* __restrict__ tau1p,
                             const float* __restrict__ alphap,
                             float* __restrict__ ws){
  const int b = blockIdx.x;
  const int t = threadIdx.x;
  __shared__ float te[NTEMB], ste[NTEMB], hid[NHID], red[64];
  __shared__ float tau_sh;
  {
    float v = temb[(size_t)b*NTEMB + t];   // blockDim == NTEMB == 256
    te[t] = v;
    ste[t] = v * sigf(v);
  }
  __syncthreads();
  if(t<NHID){
    float acc = b1[t];
    const float* wrow = w1 + (size_t)t*NTEMB;
    for(int k=0;k<NTEMB;k++) acc = fmaf(te[k], wrow[k], acc);
    hid[t] = acc * sigf(acc);
  }
  __syncthreads();
  if(t<64) red[t] = hid[t]*w2[t] + hid[t+64]*w2[t+64];
  __syncthreads();
  if(t==0){
    float s = 0.0f;
    for(int i=0;i<64;i++) s += red[i];
    float st = tanhf(s + b2[0]);
    tau_sh = tau0p[0] + softplusf(tau1p[0])*st;
  }
  __syncthreads();
  const float alpha = softplusf(alphap[0]) + 1e-12f;
  const float tau = tau_sh;
  for(int m=t; m<NM; m+=256){
    float ka = fabsf(ws[OFF_KAPPA+m]);
    ws[OFF_GATE + b*NM + m] = ws[OFF_BAND+m] * sigf(alpha*(tau-ka));
  }
  if(t<NCH){
    float acc = tprojb[t];
    const float* wrow = tprojw + (size_t)t*NTEMB;
    for(int k=0;k<NTEMB;k++) acc = fmaf(ste[k], wrow[k], acc);
    ws[OFF_TCOND + b*NCH + t] = acc;
  }
}

// ---------------------------------------------------------------- analysis
// grid (NMT, NS, NB); block 256.
// Thread owns 2 channels x 4 m. Partial sums over its n-segment to ws.
__global__ __launch_bounds__(256)
void k_analysis(const float* __restrict__ xf, const float* __restrict__ z,
                const float* __restrict__ gaborc,
                float* __restrict__ ws, int nsegLen){
  __shared__ float xs[NCH][68];            // [c][n] padded: +68 keeps b128 align + spreads banks
  __shared__ float cws[NCHUNK][MT];        // [n][m]
  __shared__ float sws[NCHUNK][MT];
  __shared__ float zs[NCHUNK];
  __shared__ float kap_s[MT], gc_s[MT], iom_s[MT];

  const int t = threadIdx.x;
  const int b = blockIdx.z, mt = blockIdx.x, ns = blockIdx.y;
  const int m0 = mt*MT;

  if(t<MT){
    int mg = min(m0+t, NM-1);
    kap_s[t] = ws[OFF_KAPPA+mg];
    gc_s[t]  = gaborc[mg];
    iom_s[t] = 1.0f/ws[OFF_OMEGA+mg];
  }

  // staging roles
  const int cst = t>>2;            // 0..63
  const int j0  = (t&3)*4;         // 0,4,8,12
  const float tc = ws[OFF_TCOND + b*NCH + cst];

  // compute roles
  const int mq = t&7;              // m-quad (4 m)
  const int cg = t>>3;             // 0..31 -> 2 channels
  const int c0 = 2*cg;

  float ar0[4]={0,0,0,0}, ai0[4]={0,0,0,0};
  float ar1[4]={0,0,0,0}, ai1[4]={0,0,0,0};

  const int nbase0 = ns*nsegLen;
  const float* xrowBase = xf + ((size_t)b*NCH + cst)*NPTS;

  for(int nb = nbase0; nb < nbase0+nsegLen; nb += NCHUNK){
    __syncthreads();                                   // prev chunk reads done
    if(t<NCHUNK) zs[t] = z[(size_t)b*NPTS + nb + t];
    const float* xrow = xrowBase + nb;
    #pragma unroll
    for(int i=0;i<4;i++){
      float4 v = *(const float4*)(xrow + j0 + 16*i);
      v.x += tc; v.y += tc; v.z += tc; v.w += tc;
      *(float4*)&xs[cst][j0 + 16*i] = v;
    }
    __syncthreads();                                   // zs/xs ready
    {
      const int m = t&31, nn = t>>5;
      const float kap = kap_s[m], gcv = gc_s[m], iom = iom_s[m];
      #pragma unroll
      for(int j=0;j<8;j++){
        int n = nn + 8*j;
        float zv = zs[n];
        float th = zv*kap;
        float sv = __sinf(th);                         // v_sin_f32 path
        float cv = __cosf(th);                         // v_cos_f32 path
        float e = fmaf(zv, INV_PI, -gcv)*iom;
        float w = __expf(-0.5f*e*e);                   // v_exp_f32 path
        cws[n][m] = cv*w;
        sws[n][m] = sv*w;
      }
    }
    __syncthreads();                                   // basis ready
    #pragma unroll 2
    for(int n=0;n<NCHUNK;n++){
      float x0 = xs[c0  ][n];
      float x1 = xs[c0+1][n];
      float4 c4 = *(const float4*)&cws[n][mq*4];
      float4 s4 = *(const float4*)&sws[n][mq*4];
      float cv4[4]={c4.x,c4.y,c4.z,c4.w};
      float sv4[4]={s4.x,s4.y,s4.z,s4.w};
      #pragma unroll
      for(int q=0;q<4;q++){
        ar0[q] = fmaf(x0, cv4[q], ar0[q]);
        ai0[q] = fmaf(x0, sv4[q], ai0[q]);
        ar1[q] = fmaf(x1, cv4[q], ar1[q]);
        ai1[q] = fmaf(x1, sv4[q], ai1[q]);
      }
    }
  }
  const int NSg = gridDim.y;
  float* pr = ws + OFF_PART + (size_t)(ns*NB + b)*NM*NCH;
  float* pi = pr + (size_t)NSg*BMC;
  #pragma unroll
  for(int q=0;q<4;q++){
    int m = m0 + mq*4 + q;
    if(m < NM){
      pr[(size_t)m*NCH + c0  ] = ar0[q];
      pr[(size_t)m*NCH + c0+1] = ar1[q];
      pi[(size_t)m*NCH + c0  ] = ai0[q];
      pi[(size_t)m*NCH + c0+1] = ai1[q];
    }
  }
}

// ---------------------------------------------------------------- reduce + gate + spectral multiply
__global__ void k_reduce_mult(const float* __restrict__ wr, const float* __restrict__ wi,
                              float* __restrict__ ws, int NS){
  int idx = blockIdx.x*256 + threadIdx.x;
  if(idx >= BMC) return;
  int c = idx & 63;
  int m = (idx >> 6) % NM;
  int b = idx / (NM*NCH);
  const float* part = ws + OFF_PART;
  size_t ph = (size_t)NS*BMC;
  float sr=0.0f, si=0.0f;
  for(int s=0;s<NS;s++){
    size_t o = ((size_t)(s*NB + b)*NM + m)*NCH + c;
    sr += part[o];
    si += part[o+ph];
  }
  float g  = ws[OFF_GATE + b*NM + m] * (1.0f/(float)NPTS);
  float Xr =  g*sr;
  float Xi = -g*si;
  float wrv = wr[(size_t)c*NM+m], wiv = wi[(size_t)c*NM+m];
  ws[OFF_YR + idx] =   Xr*wrv - Xi*wiv;
  ws[OFF_YI + idx] = -(Xr*wiv + Xi*wrv);    // pre-negated: synthesis is pure +FMA
}

// ---------------------------------------------------------------- synthesis
// grid (NPTS/64, NB); block 256. Thread owns 4c x 4n.
__global__ __launch_bounds__(256)
void k_synth(const float* __restrict__ z, const float* __restrict__ gaborc,
             const float* __restrict__ bias, const float* __restrict__ ws,
             float* __restrict__ out){
  __shared__ float yrs[MT][68], yis[MT][68];   // [m][c] padded
  __shared__ float cws[MT][NCHUNK], sws[MT][NCHUNK]; // [m][n]
  __shared__ float zs[NCHUNK];
  __shared__ float kap_s[MT], gc_s[MT], iom_s[MT];

  const int t = threadIdx.x;
  const int b = blockIdx.y;
  const int nb = blockIdx.x*NCHUNK;
  const int ci = t&15, ni = t>>4;

  if(t<NCHUNK) zs[t] = z[(size_t)b*NPTS + nb + t];

  float acc[4][4] = {};

  for(int mcb=0; mcb<NM; mcb+=MT){
    __syncthreads();                                 // prev chunk reads done (also covers zs)
    if(t<MT){
      int mg = min(mcb+t, NM-1);
      kap_s[t] = ws[OFF_KAPPA+mg];
      gc_s[t]  = gaborc[mg];
      iom_s[t] = 1.0f/ws[OFF_OMEGA+mg];
    }
    #pragma unroll
    for(int e=0;e<2;e++){
      int fi = t + e*256;          // 512 float4 slots = 32m x 64c
      int m  = fi >> 4;
      int cc = (fi & 15) << 2;
      float4 vr, vi;
      if(mcb + m < NM){
        size_t o_ = ((size_t)b*NM + (mcb+m))*NCH + cc;
        vr = *(const float4*)(ws + OFF_YR + o_);
        vi = *(const float4*)(ws + OFF_YI + o_);
      } else {
        vr = make_float4(0,0,0,0); vi = vr;          // zero-pad tail m
      }
      *(float4*)&yrs[m][cc] = vr;
      *(float4*)&yis[m][cc] = vi;
    }
    __syncthreads();                                 // kap_s / Y ready
    {
      int n = t&63, mm = t>>6;
      float zv = zs[n], zp = zv*INV_PI;
      #pragma unroll
      for(int j=0;j<8;j++){
        int m = mm + 4*j;
        float th = zv*kap_s[m];
        float sv = __sinf(th);
        float cv = __cosf(th);
        float e = (zp - gc_s[m])*iom_s[m];
        float w = __expf(-0.5f*e*e);
        cws[m][n] = cv*w;
        sws[m][n] = sv*w;
      }
    }
    __syncthreads();                                 // basis ready
    #pragma unroll 4
    for(int m=0;m<MT;m++){
      float4 yr4 = *(const float4*)&yrs[m][ci<<2];
      float4 yi4 = *(const float4*)&yis[m][ci<<2];
      float4 c4  = *(const float4*)&cws[m][ni<<2];
      float4 s4  = *(const float4*)&sws[m][ni<<2];
      float yrv[4]={yr4.x,yr4.y,yr4.z,yr4.w};
      float yiv[4]={yi4.x,yi4.y,yi4.z,yi4.w};
      float cv4[4]={c4.x,c4.y,c4.z,c4.w};
      float sv4[4]={s4.x,s4.y,s4.z,s4.w};
      #pragma unroll
      for(int a=0;a<4;a++){
        #pragma unroll
        for(int q=0;q<4;q++){
          acc[a][q] = fmaf(yrv[a], cv4[q], acc[a][q]);
          acc[a][q] = fmaf(yiv[a], sv4[q], acc[a][q]);   // yi pre-negated
        }
      }
    }
  }
  #pragma unroll
  for(int a=0;a<4;a++){
    int c = (ci<<2) + a;
    float bv = bias[c];
    float4 v;
    v.x = acc[a][0]+bv; v.y = acc[a][1]+bv; v.z = acc[a][2]+bv; v.w = acc[a][3]+bv;
    *(float4*)(out + ((size_t)b*NCH + c)*NPTS + nb + (ni<<2)) = v;
  }
}

// ---------------------------------------------------------------- launch
extern "C" void kernel_launch(void* const* d_in, const int* in_sizes, int n_in,
                              void* d_out, int out_size, void* d_ws, size_t ws_size,
                              hipStream_t stream){
  const float* x_feat = (const float*)d_in[0];
  const float* z      = (const float*)d_in[1];
  const float* temb   = (const float*)d_in[2];
  const float* kraw   = (const float*)d_in[3];
  const float* gaborc = (const float*)d_in[4];
  const float* gom    = (const float*)d_in[5];
  const float* wr     = (const float*)d_in[6];
  const float* wi     = (const float*)d_in[7];
  const float* bias   = (const float*)d_in[8];
  const float* tprojw = (const float*)d_in[9];
  const float* tprojb = (const float*)d_in[10];
  const float* w1     = (const float*)d_in[11];
  const float* b1     = (const float*)d_in[12];
  const float* w2     = (const float*)d_in[13];
  const float* b2     = (const float*)d_in[14];
  const float* tau0   = (const float*)d_in[15];
  const float* tau1   = (const float*)d_in[16];
  const float* alphar = (const float*)d_in[17];
  const float* glow   = (const float*)d_in[18];
  const float* gmid   = (const float*)d_in[19];
  const float* ghigh  = (const float*)d_in[20];
  float* out = (float*)d_out;
  float* ws  = (float*)d_ws;

  // occupancy: NS=16 -> 2304 blocks = 9/CU queued (exact, no tail), 4 resident by LDS.
  // cascade by available workspace; identical work per call for a given ws_size
  // (graph-capture safe: NS is a pure function of ws_size).
  int NS = 16;
  while(NS > 1 && ws_size < (size_t)(OFF_PART + 2*(size_t)NS*BMC)*sizeof(float)) NS >>= 1;

  k_prep_freq <<<1, 256, 0, stream>>>(kraw, gom, glow, gmid, ghigh, ws);
  k_prep_batch<<<NB, 256, 0, stream>>>(temb, w1, b1, w2, b2, tprojw, tprojb,
                                       tau0, tau1, alphar, ws);
  k_analysis  <<<dim3(NMT, NS, NB), 256, 0, stream>>>(x_feat, z, gaborc, ws, NPTS/NS);
  k_reduce_mult<<<(BMC+255)/256, 256, 0, stream>>>(wr, wi, ws, NS);
  k_synth     <<<dim3(NPTS/NCHUNK, NB), 256, 0, stream>>>(z, gaborc, bias, ws, out);
}

// Round 9
// 295.541 us; speedup vs baseline: 1.2487x; 1.0780x over previous
//
#include <hip/hip_runtime.h>
#include <math.h>

#define NB 16
#define NCH 64
#define NPTS 4096
#define NM 257
#define NKF 128
#define NTEMB 256
#define NHID 128

#define MT 32          // analysis m-tile
#define NMT 9          // ceil(257/32)
#define NCK 32         // n-chunk (both hot kernels)
#define SMT 16         // synth m-tile

#define INV_PI 0.31830988618379067154f

typedef float v2f __attribute__((ext_vector_type(2)));

// ---- workspace layout (float offsets) ----
#define OFF_KAPPA 0
#define OFF_OMEGA 320
#define OFF_BAND  640
#define OFF_GATE  960              // NB*NM = 4112 -> reserve 4160
#define OFF_TCOND 5120             // NB*NCH = 1024
#define OFF_YR    6144
#define BMC       263168           // NB*NM*NCH
#define OFF_YI    (OFF_YR + BMC)
#define OFF_PART  (OFF_YI + BMC)   // NS*BMC (real) then NS*BMC (imag)

__device__ __forceinline__ float sigf(float x){ return 1.0f/(1.0f+expf(-x)); }
__device__ __forceinline__ float softplusf(float x){ return (x>20.0f)? x : log1pf(expf(x)); }

// ---------------------------------------------------------------- prep_freq
__global__ void k_prep_freq(const float* __restrict__ kraw,
                            const float* __restrict__ gom,
                            const float* __restrict__ glow,
                            const float* __restrict__ gmid,
                            const float* __restrict__ ghigh,
                            float* __restrict__ ws){
  __shared__ float sp[NKF];
  __shared__ float kpos[NKF];
  __shared__ float th_s[2];
  const int t = threadIdx.x;
  if(t<NKF) sp[t] = softplusf(kraw[t]);       // parallel softplus
  __syncthreads();
  if(t==0){
    float acc = 0.0f;
    for(int k=0;k<NKF;k++){ acc += sp[k]; kpos[k]=acc; }   // short serial cumsum
    // sorted |kappa| = [0, kpos[0],kpos[0], kpos[1],kpos[1], ...]
    // q=0.4: pos=102.4 -> a[102]=kpos[50], a[103]=kpos[51]
    // q=0.8: pos=204.8 -> a[204]=kpos[101], a[205]=kpos[102]
    th_s[0] = 0.6f*kpos[50]  + 0.4f*kpos[51];
    th_s[1] = 0.2f*kpos[101] + 0.8f*kpos[102];
  }
  __syncthreads();
  const float th1 = th_s[0], th2 = th_s[1];
  const float gl = sigf(glow[0]), gm = sigf(gmid[0]), gh = sigf(ghigh[0]);
  for(int m=t; m<NM; m+=blockDim.x){
    float kap = (m<NKF) ? -kpos[NKF-1-m] : ((m==NKF) ? 0.0f : kpos[m-NKF-1]);
    float ka = fabsf(kap);
    float band = (ka<=th1) ? gl : ((ka<=th2) ? gm : gh);
    float om = fmaxf(softplusf(gom[m]), 1e-6f);
    ws[OFF_KAPPA+m] = kap;
    ws[OFF_BAND +m] = band;
    ws[OFF_OMEGA+m] = om;
  }
}

// ---------------------------------------------------------------- prep_batch
__global__ void k_prep_batch(const float* __restrict__ temb,
                             const float* __restrict__ w1, const float* __restrict__ b1,
                             const float* __restrict__ w2, const float* __restrict__ b2,
                             const float* __restrict__ tprojw, const float* __restrict__ tprojb,
                             const float* __restrict__ tau0p, const float* __restrict__ tau1p,
                             const float* __restrict__ alphap,
                             float* __restrict__ ws){
  const int b = blockIdx.x;
  const int t = threadIdx.x;
  __shared__ float te[NTEMB], ste[NTEMB], hid[NHID], red[64];
  __shared__ float tau_sh;
  {
    float v = temb[(size_t)b*NTEMB + t];   // blockDim == NTEMB == 256
    te[t] = v;
    ste[t] = v * sigf(v);
  }
  __syncthreads();
  if(t<NHID){
    float acc = b1[t];
    const float4* w4 = (const float4*)(w1 + (size_t)t*NTEMB);
    for(int k=0;k<NTEMB/4;k++){
      float4 wv = w4[k];
      acc = fmaf(te[4*k  ], wv.x, acc);
      acc = fmaf(te[4*k+1], wv.y, acc);
      acc = fmaf(te[4*k+2], wv.z, acc);
      acc = fmaf(te[4*k+3], wv.w, acc);
    }
    hid[t] = acc * sigf(acc);
  }
  __syncthreads();
  if(t<64) red[t] = hid[t]*w2[t] + hid[t+64]*w2[t+64];
  __syncthreads();
  if(t==0){
    float s = 0.0f;
    for(int i=0;i<64;i++) s += red[i];
    float st = tanhf(s + b2[0]);
    tau_sh = tau0p[0] + softplusf(tau1p[0])*st;
  }
  __syncthreads();
  const float alpha = softplusf(alphap[0]) + 1e-12f;
  const float tau = tau_sh;
  for(int m=t; m<NM; m+=256){
    float ka = fabsf(ws[OFF_KAPPA+m]);
    ws[OFF_GATE + b*NM + m] = ws[OFF_BAND+m] * sigf(alpha*(tau-ka));
  }
  if(t<NCH){
    float acc = tprojb[t];
    const float4* w4 = (const float4*)(tprojw + (size_t)t*NTEMB);
    for(int k=0;k<NTEMB/4;k++){
      float4 wv = w4[k];
      acc = fmaf(ste[4*k  ], wv.x, acc);
      acc = fmaf(ste[4*k+1], wv.y, acc);
      acc = fmaf(ste[4*k+2], wv.z, acc);
      acc = fmaf(ste[4*k+3], wv.w, acc);
    }
    ws[OFF_TCOND + b*NCH + t] = acc;
  }
}

// ---------------------------------------------------------------- analysis
// grid (NMT, NS, NB); block 256 = 4 waves. LDS ~17.9 KB -> 8 blocks/CU.
// Thread owns 2 channels x 4 m (as 2 m-pairs, v_pk_fma).
__global__ __launch_bounds__(256, 8)
void k_analysis(const float* __restrict__ xf, const float* __restrict__ z,
                const float* __restrict__ gaborc,
                float* __restrict__ ws, int nsegLen){
  __shared__ float xs[NCH][36];            // [c][n], row 144B (16B-mult), bank-spread
  __shared__ float cws[NCK][MT];           // [n][m]
  __shared__ float sws[NCK][MT];
  __shared__ float zs[NCK];
  __shared__ float kap_s[MT], gc_s[MT], iom_s[MT];

  const int t = threadIdx.x;
  const int b = blockIdx.z, mt = blockIdx.x, ns = blockIdx.y;
  const int m0 = mt*MT;

  if(t<MT){
    int mg = min(m0+t, NM-1);
    kap_s[t] = ws[OFF_KAPPA+mg];
    gc_s[t]  = gaborc[mg];
    iom_s[t] = 1.0f/ws[OFF_OMEGA+mg];
  }

  // staging roles: 64c x 32n, 8 floats (2 float4) per thread
  const int cst = t>>2;            // 0..63
  const int j0  = (t&3)*4;         // 0,4,8,12
  const float tc = ws[OFF_TCOND + b*NCH + cst];

  // compute roles
  const int mq = t&7;              // m-quad (4 m = 2 v2f)
  const int cg = t>>3;             // 0..31 -> 2 channels
  const int c0 = 2*cg;

  v2f ar0[2]={{0,0},{0,0}}, ai0[2]={{0,0},{0,0}};
  v2f ar1[2]={{0,0},{0,0}}, ai1[2]={{0,0},{0,0}};

  const int nbase0 = ns*nsegLen;
  const float* xrowBase = xf + ((size_t)b*NCH + cst)*NPTS;

  for(int nb = nbase0; nb < nbase0+nsegLen; nb += NCK){
    __syncthreads();                                   // prev chunk reads done
    if(t<NCK) zs[t] = z[(size_t)b*NPTS + nb + t];
    const float* xrow = xrowBase + nb;
    #pragma unroll
    for(int i=0;i<2;i++){
      float4 v = *(const float4*)(xrow + j0 + 16*i);
      v.x += tc; v.y += tc; v.z += tc; v.w += tc;
      *(float4*)&xs[cst][j0 + 16*i] = v;
    }
    __syncthreads();                                   // zs/xs ready
    {
      const int m = t&31, nn = t>>5;                   // 4 (n,m) sets per thread
      const float kap = kap_s[m], gcv = gc_s[m], iom = iom_s[m];
      #pragma unroll
      for(int j=0;j<4;j++){
        int n = nn + 8*j;
        float zv = zs[n];
        float th = zv*kap;
        float sv = __sinf(th);
        float cv = __cosf(th);
        float e = fmaf(zv, INV_PI, -gcv)*iom;
        float w = __expf(-0.5f*e*e);
        cws[n][m] = cv*w;
        sws[n][m] = sv*w;
      }
    }
    __syncthreads();                                   // basis ready
    #pragma unroll 4
    for(int n=0;n<NCK;n++){
      float x0 = xs[c0  ][n];
      float x1 = xs[c0+1][n];
      float4 c4 = *(const float4*)&cws[n][mq*4];
      float4 s4 = *(const float4*)&sws[n][mq*4];
      v2f cA = {c4.x,c4.y}, cB = {c4.z,c4.w};
      v2f sA = {s4.x,s4.y}, sB = {s4.z,s4.w};
      v2f x0v = {x0,x0}, x1v = {x1,x1};
      ar0[0] = __builtin_elementwise_fma(x0v, cA, ar0[0]);
      ar0[1] = __builtin_elementwise_fma(x0v, cB, ar0[1]);
      ai0[0] = __builtin_elementwise_fma(x0v, sA, ai0[0]);
      ai0[1] = __builtin_elementwise_fma(x0v, sB, ai0[1]);
      ar1[0] = __builtin_elementwise_fma(x1v, cA, ar1[0]);
      ar1[1] = __builtin_elementwise_fma(x1v, cB, ar1[1]);
      ai1[0] = __builtin_elementwise_fma(x1v, sA, ai1[0]);
      ai1[1] = __builtin_elementwise_fma(x1v, sB, ai1[1]);
    }
  }
  const int NSg = gridDim.y;
  float* pr = ws + OFF_PART + (size_t)(ns*NB + b)*NM*NCH;
  float* pi = pr + (size_t)NSg*BMC;
  #pragma unroll
  for(int q=0;q<4;q++){
    int m = m0 + mq*4 + q;
    if(m < NM){
      pr[(size_t)m*NCH + c0  ] = ar0[q>>1][q&1];
      pr[(size_t)m*NCH + c0+1] = ar1[q>>1][q&1];
      pi[(size_t)m*NCH + c0  ] = ai0[q>>1][q&1];
      pi[(size_t)m*NCH + c0+1] = ai1[q>>1][q&1];
    }
  }
}

// ---------------------------------------------------------------- reduce + gate + spectral multiply
__global__ void k_reduce_mult(const float* __restrict__ wr, const float* __restrict__ wi,
                              float* __restrict__ ws, int NS){
  int idx = blockIdx.x*256 + threadIdx.x;
  if(idx >= BMC) return;
  int c = idx & 63;
  int m = (idx >> 6) % NM;
  int b = idx / (NM*NCH);
  const float* part = ws + OFF_PART;
  size_t ph = (size_t)NS*BMC;
  float sr=0.0f, si=0.0f;
  for(int s=0;s<NS;s++){
    size_t o = ((size_t)(s*NB + b)*NM + m)*NCH + c;
    sr += part[o];
    si += part[o+ph];
  }
  float g  = ws[OFF_GATE + b*NM + m] * (1.0f/(float)NPTS);
  float Xr =  g*sr;
  float Xi = -g*si;
  float wrv = wr[(size_t)c*NM+m], wiv = wi[(size_t)c*NM+m];
  ws[OFF_YR + idx] =   Xr*wrv - Xi*wiv;
  ws[OFF_YI + idx] = -(Xr*wiv + Xi*wrv);    // pre-negated: synthesis is pure +FMA
}

// ---------------------------------------------------------------- synthesis
// grid (NPTS/NCK, NB) = 2048 blocks = 8/CU exact. LDS ~13.1 KB.
// Thread owns 4c x 2n (v_pk_fma over the n-pair).
__global__ __launch_bounds__(256, 8)
void k_synth(const float* __restrict__ z, const float* __restrict__ gaborc,
             const float* __restrict__ bias, const float* __restrict__ ws,
             float* __restrict__ out){
  __shared__ float yrs[SMT][64], yis[SMT][64];   // [m][c]
  __shared__ float cws[SMT][36], sws[SMT][36];   // [m][n] (+pad)
  __shared__ float zs[NCK];
  __shared__ float kap_s[SMT], gc_s[SMT], iom_s[SMT];

  const int t = threadIdx.x;
  const int b = blockIdx.y;
  const int nb = blockIdx.x*NCK;
  const int c0 = (t>>4)<<2;        // 0,4,...,60
  const int n0 = (t&15)<<1;        // 0,2,...,30

  if(t<NCK) zs[t] = z[(size_t)b*NPTS + nb + t];

  v2f acc[4] = {{0,0},{0,0},{0,0},{0,0}};

  for(int mcb=0; mcb<NM; mcb+=SMT){
    __syncthreads();                                 // prev tile reads done (also covers zs)
    if(t<SMT){
      int mg = min(mcb+t, NM-1);
      kap_s[t] = ws[OFF_KAPPA+mg];
      gc_s[t]  = gaborc[mg];
      iom_s[t] = 1.0f/ws[OFF_OMEGA+mg];
    }
    {
      // Y stage: 256 slots = 16m x 16 c-quads
      int m  = t >> 4;
      int cc = (t & 15) << 2;
      float4 vr, vi;
      if(mcb + m < NM){
        size_t o_ = ((size_t)b*NM + (mcb+m))*NCH + cc;
        vr = *(const float4*)(ws + OFF_YR + o_);
        vi = *(const float4*)(ws + OFF_YI + o_);
      } else {
        vr = make_float4(0,0,0,0); vi = vr;          // zero-pad tail m
      }
      *(float4*)&yrs[m][cc] = vr;
      *(float4*)&yis[m][cc] = vi;
    }
    __syncthreads();                                 // kap_s / Y ready
    {
      int n = t&31, mm = t>>5;                       // 2 (m,n) sets per thread
      float zv = zs[n], zp = zv*INV_PI;
      #pragma unroll
      for(int j=0;j<2;j++){
        int m = mm + 8*j;
        float th = zv*kap_s[m];
        float sv = __sinf(th);
        float cv = __cosf(th);
        float e = (zp - gc_s[m])*iom_s[m];
        float w = __expf(-0.5f*e*e);
        cws[m][n] = cv*w;
        sws[m][n] = sv*w;
      }
    }
    __syncthreads();                                 // basis ready
    #pragma unroll 4
    for(int m=0;m<SMT;m++){
      float4 yr4 = *(const float4*)&yrs[m][c0];
      float4 yi4 = *(const float4*)&yis[m][c0];
      v2f cv2 = *(const v2f*)&cws[m][n0];
      v2f sv2 = *(const v2f*)&sws[m][n0];
      float yrv[4]={yr4.x,yr4.y,yr4.z,yr4.w};
      float yiv[4]={yi4.x,yi4.y,yi4.z,yi4.w};
      #pragma unroll
      for(int a=0;a<4;a++){
        v2f yr = {yrv[a],yrv[a]};
        v2f yi = {yiv[a],yiv[a]};
        acc[a] = __builtin_elementwise_fma(yr, cv2, acc[a]);
        acc[a] = __builtin_elementwise_fma(yi, sv2, acc[a]);   // yi pre-negated
      }
    }
  }
  #pragma unroll
  for(int a=0;a<4;a++){
    int c = c0 + a;
    float bv = bias[c];
    float2 v;
    v.x = acc[a][0]+bv; v.y = acc[a][1]+bv;
    *(float2*)(out + ((size_t)b*NCH + c)*NPTS + nb + n0) = v;
  }
}

// ---------------------------------------------------------------- launch
extern "C" void kernel_launch(void* const* d_in, const int* in_sizes, int n_in,
                              void* d_out, int out_size, void* d_ws, size_t ws_size,
                              hipStream_t stream){
  const float* x_feat = (const float*)d_in[0];
  const float* z      = (const float*)d_in[1];
  const float* temb   = (const float*)d_in[2];
  const float* kraw   = (const float*)d_in[3];
  const float* gaborc = (const float*)d_in[4];
  const float* gom    = (const float*)d_in[5];
  const float* wr     = (const float*)d_in[6];
  const float* wi     = (const float*)d_in[7];
  const float* bias   = (const float*)d_in[8];
  const float* tprojw = (const float*)d_in[9];
  const float* tprojb = (const float*)d_in[10];
  const float* w1     = (const float*)d_in[11];
  const float* b1     = (const float*)d_in[12];
  const float* w2     = (const float*)d_in[13];
  const float* b2     = (const float*)d_in[14];
  const float* tau0   = (const float*)d_in[15];
  const float* tau1   = (const float*)d_in[16];
  const float* alphar = (const float*)d_in[17];
  const float* glow   = (const float*)d_in[18];
  const float* gmid   = (const float*)d_in[19];
  const float* ghigh  = (const float*)d_in[20];
  float* out = (float*)d_out;
  float* ws  = (float*)d_ws;

  // occupancy: NS=32 -> 4608 blocks = 18/CU queued at 8 resident (small tail).
  // cascade by available workspace; NS is a pure function of ws_size (capture-safe).
  int NS = 32;
  while(NS > 1 && ws_size < (size_t)(OFF_PART + 2*(size_t)NS*BMC)*sizeof(float)) NS >>= 1;

  k_prep_freq <<<1, 256, 0, stream>>>(kraw, gom, glow, gmid, ghigh, ws);
  k_prep_batch<<<NB, 256, 0, stream>>>(temb, w1, b1, w2, b2, tprojw, tprojb,
                                       tau0, tau1, alphar, ws);
  k_analysis  <<<dim3(NMT, NS, NB), 256, 0, stream>>>(x_feat, z, gaborc, ws, NPTS/NS);
  k_reduce_mult<<<(BMC+255)/256, 256, 0, stream>>>(wr, wi, ws, NS);
  k_synth     <<<dim3(NPTS/NCK, NB), 256, 0, stream>>>(z, gaborc, bias, ws, out);
}

// Round 10
// 271.601 us; speedup vs baseline: 1.3588x; 1.0881x over previous
//
#include <hip/hip_runtime.h>
#include <math.h>

#define NB 16
#define NCH 64
#define NPTS 4096
#define NM 257
#define NKF 128
#define NTEMB 256
#define NHID 128

#define MT 32          // analysis m-tile
#define NMT 9          // ceil(257/32)
#define NCK 32         // analysis n-chunk
#define SMT 32         // synth m-tile
#define SNCK 64        // synth n-chunk
#define NTILE 9        // ceil(257/32)

#define INV_PI 0.31830988618379067154f

typedef float v2f __attribute__((ext_vector_type(2)));

// ---- workspace layout (float offsets) ----
#define OFF_KAPPA 0
#define OFF_OMEGA 320
#define OFF_BAND  640
#define OFF_GATE  960              // NB*NM = 4112 -> reserve 4160
#define OFF_TCOND 5120             // NB*NCH = 1024
#define OFF_YR    6144
#define BMC       263168           // NB*NM*NCH
#define OFF_YI    (OFF_YR + BMC)
#define OFF_PART  (OFF_YI + BMC)   // NS*BMC (real) then NS*BMC (imag)

__device__ __forceinline__ float sigf(float x){ return 1.0f/(1.0f+expf(-x)); }
__device__ __forceinline__ float softplusf(float x){ return (x>20.0f)? x : log1pf(expf(x)); }

// ---------------------------------------------------------------- fused prep
// grid 16 blocks: block b does batch b's MLP/gate/tcond; every block computes
// the (cheap) freq arrays locally; block 0 additionally writes them to ws.
__global__ void k_prep(const float* __restrict__ kraw, const float* __restrict__ gom,
                       const float* __restrict__ glow, const float* __restrict__ gmid,
                       const float* __restrict__ ghigh,
                       const float* __restrict__ temb,
                       const float* __restrict__ w1, const float* __restrict__ b1,
                       const float* __restrict__ w2, const float* __restrict__ b2,
                       const float* __restrict__ tprojw, const float* __restrict__ tprojb,
                       const float* __restrict__ tau0p, const float* __restrict__ tau1p,
                       const float* __restrict__ alphap,
                       float* __restrict__ ws){
  const int b = blockIdx.x;
  const int t = threadIdx.x;
  __shared__ float sp[NKF], kpos[NKF], th_s[2];
  __shared__ float te[NTEMB], ste[NTEMB], hid[NHID], red[64];
  __shared__ float tau_sh;

  if(t<NKF) sp[t] = softplusf(kraw[t]);
  {
    float v = temb[(size_t)b*NTEMB + t];   // blockDim == 256 == NTEMB
    te[t] = v;
    ste[t] = v * sigf(v);
  }
  __syncthreads();
  // thread 0: short cumsum + quantile thresholds (sorted |kappa| interleaving:
  // q=0.4 -> 0.6*kpos[50]+0.4*kpos[51]; q=0.8 -> 0.2*kpos[101]+0.8*kpos[102])
  if(t==0){
    float acc = 0.0f;
    for(int k=0;k<NKF;k++){ acc += sp[k]; kpos[k]=acc; }
    th_s[0] = 0.6f*kpos[50]  + 0.4f*kpos[51];
    th_s[1] = 0.2f*kpos[101] + 0.8f*kpos[102];
  }
  if(t<NHID){
    float acc = b1[t];
    const float4* w4 = (const float4*)(w1 + (size_t)t*NTEMB);
    for(int k=0;k<NTEMB/4;k++){
      float4 wv = w4[k];
      acc = fmaf(te[4*k  ], wv.x, acc);
      acc = fmaf(te[4*k+1], wv.y, acc);
      acc = fmaf(te[4*k+2], wv.z, acc);
      acc = fmaf(te[4*k+3], wv.w, acc);
    }
    hid[t] = acc * sigf(acc);
  }
  __syncthreads();
  if(t<64) red[t] = hid[t]*w2[t] + hid[t+64]*w2[t+64];
  __syncthreads();
  if(t==0){
    float s = 0.0f;
    for(int i=0;i<64;i++) s += red[i];
    float st = tanhf(s + b2[0]);
    tau_sh = tau0p[0] + softplusf(tau1p[0])*st;
  }
  __syncthreads();
  const float th1 = th_s[0], th2 = th_s[1];
  const float alpha = softplusf(alphap[0]) + 1e-12f;
  const float tau = tau_sh;
  const float gl = sigf(glow[0]), gm = sigf(gmid[0]), gh = sigf(ghigh[0]);
  for(int m=t; m<NM; m+=256){
    float kap = (m<NKF) ? -kpos[NKF-1-m] : ((m==NKF) ? 0.0f : kpos[m-NKF-1]);
    float ka = fabsf(kap);
    float band = (ka<=th1) ? gl : ((ka<=th2) ? gm : gh);
    ws[OFF_GATE + b*NM + m] = band * sigf(alpha*(tau-ka));
    if(b==0){
      ws[OFF_KAPPA+m] = kap;
      ws[OFF_BAND +m] = band;
      ws[OFF_OMEGA+m] = fmaxf(softplusf(gom[m]), 1e-6f);
    }
  }
  if(t<NCH){
    float acc = tprojb[t];
    const float4* w4 = (const float4*)(tprojw + (size_t)t*NTEMB);
    for(int k=0;k<NTEMB/4;k++){
      float4 wv = w4[k];
      acc = fmaf(ste[4*k  ], wv.x, acc);
      acc = fmaf(ste[4*k+1], wv.y, acc);
      acc = fmaf(ste[4*k+2], wv.z, acc);
      acc = fmaf(ste[4*k+3], wv.w, acc);
    }
    ws[OFF_TCOND + b*NCH + t] = acc;
  }
}

// ---------------------------------------------------------------- analysis
// grid (NMT, NS, NB); block 256 = 4 waves. LDS ~17.9 KB -> 8 blocks/CU cap.
// Thread owns 2 channels x 4 m (2 m-pairs, v_pk_fma).
__global__ __launch_bounds__(256, 8)
void k_analysis(const float* __restrict__ xf, const float* __restrict__ z,
                const float* __restrict__ gaborc,
                float* __restrict__ ws, int nsegLen){
  __shared__ float xs[NCH][36];            // [c][n]
  __shared__ float cws[NCK][MT];           // [n][m]
  __shared__ float sws[NCK][MT];
  __shared__ float zs[NCK];
  __shared__ float kap_s[MT], gc_s[MT], iom_s[MT];

  const int t = threadIdx.x;
  const int b = blockIdx.z, mt = blockIdx.x, ns = blockIdx.y;
  const int m0 = mt*MT;

  if(t<MT){
    int mg = min(m0+t, NM-1);
    kap_s[t] = ws[OFF_KAPPA+mg];
    gc_s[t]  = gaborc[mg];
    iom_s[t] = 1.0f/ws[OFF_OMEGA+mg];
  }

  const int cst = t>>2;            // staging: 0..63
  const int j0  = (t&3)*4;
  const float tc = ws[OFF_TCOND + b*NCH + cst];

  const int mq = t&7;              // compute: m-quad
  const int cg = t>>3;
  const int c0 = 2*cg;

  v2f ar0[2]={{0,0},{0,0}}, ai0[2]={{0,0},{0,0}};
  v2f ar1[2]={{0,0},{0,0}}, ai1[2]={{0,0},{0,0}};

  const int nbase0 = ns*nsegLen;
  const float* xrowBase = xf + ((size_t)b*NCH + cst)*NPTS;

  for(int nb = nbase0; nb < nbase0+nsegLen; nb += NCK){
    __syncthreads();
    if(t<NCK) zs[t] = z[(size_t)b*NPTS + nb + t];
    const float* xrow = xrowBase + nb;
    #pragma unroll
    for(int i=0;i<2;i++){
      float4 v = *(const float4*)(xrow + j0 + 16*i);
      v.x += tc; v.y += tc; v.z += tc; v.w += tc;
      *(float4*)&xs[cst][j0 + 16*i] = v;
    }
    __syncthreads();
    {
      const int m = t&31, nn = t>>5;
      const float kap = kap_s[m], gcv = gc_s[m], iom = iom_s[m];
      #pragma unroll
      for(int j=0;j<4;j++){
        int n = nn + 8*j;
        float zv = zs[n];
        float th = zv*kap;
        float sv = __sinf(th);
        float cv = __cosf(th);
        float e = fmaf(zv, INV_PI, -gcv)*iom;
        float w = __expf(-0.5f*e*e);
        cws[n][m] = cv*w;
        sws[n][m] = sv*w;
      }
    }
    __syncthreads();
    #pragma unroll 4
    for(int n=0;n<NCK;n++){
      float x0 = xs[c0  ][n];
      float x1 = xs[c0+1][n];
      float4 c4 = *(const float4*)&cws[n][mq*4];
      float4 s4 = *(const float4*)&sws[n][mq*4];
      v2f cA = {c4.x,c4.y}, cB = {c4.z,c4.w};
      v2f sA = {s4.x,s4.y}, sB = {s4.z,s4.w};
      v2f x0v = {x0,x0}, x1v = {x1,x1};
      ar0[0] = __builtin_elementwise_fma(x0v, cA, ar0[0]);
      ar0[1] = __builtin_elementwise_fma(x0v, cB, ar0[1]);
      ai0[0] = __builtin_elementwise_fma(x0v, sA, ai0[0]);
      ai0[1] = __builtin_elementwise_fma(x0v, sB, ai0[1]);
      ar1[0] = __builtin_elementwise_fma(x1v, cA, ar1[0]);
      ar1[1] = __builtin_elementwise_fma(x1v, cB, ar1[1]);
      ai1[0] = __builtin_elementwise_fma(x1v, sA, ai1[0]);
      ai1[1] = __builtin_elementwise_fma(x1v, sB, ai1[1]);
    }
  }
  const int NSg = gridDim.y;
  float* pr = ws + OFF_PART + (size_t)(ns*NB + b)*NM*NCH;
  float* pi = pr + (size_t)NSg*BMC;
  #pragma unroll
  for(int q=0;q<4;q++){
    int m = m0 + mq*4 + q;
    if(m < NM){
      pr[(size_t)m*NCH + c0  ] = ar0[q>>1][q&1];
      pr[(size_t)m*NCH + c0+1] = ar1[q>>1][q&1];
      pi[(size_t)m*NCH + c0  ] = ai0[q>>1][q&1];
      pi[(size_t)m*NCH + c0+1] = ai1[q>>1][q&1];
    }
  }
}

// ---------------------------------------------------------------- reduce + gate + spectral multiply
__global__ void k_reduce_mult(const float* __restrict__ wr, const float* __restrict__ wi,
                              float* __restrict__ ws, int NS){
  int idx = blockIdx.x*256 + threadIdx.x;
  if(idx >= BMC) return;
  int c = idx & 63;
  int m = (idx >> 6) % NM;
  int b = idx / (NM*NCH);
  const float* part = ws + OFF_PART;
  size_t ph = (size_t)NS*BMC;
  float sr=0.0f, si=0.0f;
  for(int s=0;s<NS;s++){
    size_t o = ((size_t)(s*NB + b)*NM + m)*NCH + c;
    sr += part[o];
    si += part[o+ph];
  }
  float g  = ws[OFF_GATE + b*NM + m] * (1.0f/(float)NPTS);
  float Xr =  g*sr;
  float Xi = -g*si;
  float wrv = wr[(size_t)c*NM+m], wiv = wi[(size_t)c*NM+m];
  ws[OFF_YR + idx] =   Xr*wrv - Xi*wiv;
  ws[OFF_YI + idx] = -(Xr*wiv + Xi*wrv);    // pre-negated: synthesis is pure +FMA
}

// ---------------------------------------------------------------- synthesis V2
// grid (NPTS/SNCK, NB) = 1024 blocks = 4/CU exact, all resident.
// LDS ~37 KB -> 4 blocks/CU. Thread owns 4c x 4n. 2 barriers/tile,
// Y prefetched into regs during compute (issue-early/write-late).
__global__ __launch_bounds__(256, 4)
void k_synth(const float* __restrict__ z, const float* __restrict__ gaborc,
             const float* __restrict__ bias, const float* __restrict__ ws,
             float* __restrict__ out){
  __shared__ float yrs[SMT][64], yis[SMT][64];     // [m][c]
  __shared__ float cws[SMT][68], sws[SMT][68];     // [m][n] (+pad)
  __shared__ float kapF[260], gcF[260], iomF[260]; // full-range tables
  __shared__ float zs[SNCK];

  const int t = threadIdx.x;
  const int b = blockIdx.y;
  const int nb = blockIdx.x*SNCK;
  const int c0 = (t>>4)<<2;        // 4c
  const int n0 = (t&15)<<2;        // 4n

  // prologue: tables + z
  for(int i=t; i<NM; i+=256){
    kapF[i] = ws[OFF_KAPPA+i];
    gcF[i]  = gaborc[i];
    iomF[i] = 1.0f/ws[OFF_OMEGA+i];
  }
  if(t<SNCK) zs[t] = z[(size_t)b*NPTS + nb + t];

  const float* yrBase = ws + OFF_YR + (size_t)b*NM*NCH;
  const float* yiBase = ws + OFF_YI + (size_t)b*NM*NCH;

  // prefetch tile 0 (slots s = t + e*256 -> contiguous floats s*4; coalesced)
  float4 pyr[2], pyi[2];
  #pragma unroll
  for(int e=0;e<2;e++){
    int s = t + e*256;
    pyr[e] = *(const float4*)(yrBase + (size_t)s*4);   // tile0: m 0..31 all < NM
    pyi[e] = *(const float4*)(yiBase + (size_t)s*4);
  }

  v2f acc[4][2] = {};

  for(int tile=0; tile<NTILE; tile++){
    const int mcb = tile*SMT;
    __syncthreads();                       // prev compute reads done; prologue visible
    // phase A: store prefetched Y; generate basis
    #pragma unroll
    for(int e=0;e<2;e++){
      int s = t + e*256;
      int m = s>>4, cc = (s&15)<<2;
      *(float4*)&yrs[m][cc] = pyr[e];
      *(float4*)&yis[m][cc] = pyi[e];
    }
    {
      int n = t&63, mm = t>>6;
      float zv = zs[n], zp = zv*INV_PI;
      #pragma unroll
      for(int j=0;j<8;j++){
        int m = mm + 4*j;
        int mg = min(mcb+m, NM-1);         // tail rows: Y==0 so value irrelevant
        float th = zv*kapF[mg];
        float sv = __sinf(th);
        float cv = __cosf(th);
        float e2 = (zp - gcF[mg])*iomF[mg];
        float w = __expf(-0.5f*e2*e2);
        cws[m][n] = cv*w;
        sws[m][n] = sv*w;
      }
    }
    __syncthreads();                       // Y + basis ready
    // phase B: prefetch next tile Y (issue early), then FMA
    if(tile+1 < NTILE){
      const int mb2 = (tile+1)*SMT;
      #pragma unroll
      for(int e=0;e<2;e++){
        int s = t + e*256;
        int mglob = mb2 + (s>>4);
        if(mglob < NM){
          size_t o = (size_t)mb2*NCH + (size_t)s*4;
          pyr[e] = *(const float4*)(yrBase + o);
          pyi[e] = *(const float4*)(yiBase + o);
        } else {
          pyr[e] = make_float4(0,0,0,0);
          pyi[e] = make_float4(0,0,0,0);
        }
      }
    }
    #pragma unroll 4
    for(int m=0;m<SMT;m++){
      float4 yr4 = *(const float4*)&yrs[m][c0];
      float4 yi4 = *(const float4*)&yis[m][c0];
      v2f cA = *(const v2f*)&cws[m][n0];
      v2f cB = *(const v2f*)&cws[m][n0+2];
      v2f sA = *(const v2f*)&sws[m][n0];
      v2f sB = *(const v2f*)&sws[m][n0+2];
      float yrv[4]={yr4.x,yr4.y,yr4.z,yr4.w};
      float yiv[4]={yi4.x,yi4.y,yi4.z,yi4.w};
      #pragma unroll
      for(int a=0;a<4;a++){
        v2f yr = {yrv[a],yrv[a]};
        v2f yi = {yiv[a],yiv[a]};
        acc[a][0] = __builtin_elementwise_fma(yr, cA, acc[a][0]);
        acc[a][0] = __builtin_elementwise_fma(yi, sA, acc[a][0]);   // yi pre-negated
        acc[a][1] = __builtin_elementwise_fma(yr, cB, acc[a][1]);
        acc[a][1] = __builtin_elementwise_fma(yi, sB, acc[a][1]);
      }
    }
  }
  #pragma unroll
  for(int a=0;a<4;a++){
    int c = c0 + a;
    float bv = bias[c];
    float4 v;
    v.x = acc[a][0][0]+bv; v.y = acc[a][0][1]+bv;
    v.z = acc[a][1][0]+bv; v.w = acc[a][1][1]+bv;
    *(float4*)(out + ((size_t)b*NCH + c)*NPTS + nb + n0) = v;
  }
}

// ---------------------------------------------------------------- launch
extern "C" void kernel_launch(void* const* d_in, const int* in_sizes, int n_in,
                              void* d_out, int out_size, void* d_ws, size_t ws_size,
                              hipStream_t stream){
  const float* x_feat = (const float*)d_in[0];
  const float* z      = (const float*)d_in[1];
  const float* temb   = (const float*)d_in[2];
  const float* kraw   = (const float*)d_in[3];
  const float* gaborc = (const float*)d_in[4];
  const float* gom    = (const float*)d_in[5];
  const float* wr     = (const float*)d_in[6];
  const float* wi     = (const float*)d_in[7];
  const float* bias   = (const float*)d_in[8];
  const float* tprojw = (const float*)d_in[9];
  const float* tprojb = (const float*)d_in[10];
  const float* w1     = (const float*)d_in[11];
  const float* b1     = (const float*)d_in[12];
  const float* w2     = (const float*)d_in[13];
  const float* b2     = (const float*)d_in[14];
  const float* tau0   = (const float*)d_in[15];
  const float* tau1   = (const float*)d_in[16];
  const float* alphar = (const float*)d_in[17];
  const float* glow   = (const float*)d_in[18];
  const float* gmid   = (const float*)d_in[19];
  const float* ghigh  = (const float*)d_in[20];
  float* out = (float*)d_out;
  float* ws  = (float*)d_ws;

  // NS=8: 1152 analysis blocks (4.5/CU, all co-resident) and small partials
  // (16.8 MB reduce reads). Pure function of ws_size (capture-safe).
  int NS = 8;
  while(NS > 1 && ws_size < (size_t)(OFF_PART + 2*(size_t)NS*BMC)*sizeof(float)) NS >>= 1;

  k_prep      <<<NB, 256, 0, stream>>>(kraw, gom, glow, gmid, ghigh, temb,
                                       w1, b1, w2, b2, tprojw, tprojb,
                                       tau0, tau1, alphar, ws);
  k_analysis  <<<dim3(NMT, NS, NB), 256, 0, stream>>>(x_feat, z, gaborc, ws, NPTS/NS);
  k_reduce_mult<<<(BMC+255)/256, 256, 0, stream>>>(wr, wi, ws, NS);
  k_synth     <<<dim3(NPTS/SNCK, NB), 256, 0, stream>>>(z, gaborc, bias, ws, out);
}

// Round 13
// 223.265 us; speedup vs baseline: 1.6529x; 1.2165x over previous
//
#include <hip/hip_runtime.h>
#include <math.h>

#define NB 16
#define NCH 64
#define NPTS 4096
#define NM 257
#define NKF 128
#define NTEMB 256
#define NHID 128

#define AMT 64         // analysis m-tile (1 m16-subtile per wave)
#define ANMT 5         // ceil(257/64)
#define ANCK 32        // analysis n-chunk (= MFMA K)
#define SMT 32         // synth m-tile
#define SNCK 64        // synth n-chunk
#define NTILE 9        // ceil(257/32)

#define INV_PI 0.31830988618379067154f

typedef float v2f __attribute__((ext_vector_type(2)));
typedef short bf16x8 __attribute__((ext_vector_type(8)));
typedef float f32x4 __attribute__((ext_vector_type(4)));
typedef unsigned short u16;

// ---- workspace layout (float offsets) ----
#define OFF_KAPPA 0
#define OFF_OMEGA 320
#define OFF_BAND  640
#define OFF_GATE  960              // NB*NM = 4112 -> reserve 4160
#define OFF_TCOND 5120             // NB*NCH = 1024
#define OFF_YR    6144
#define BMC       263168           // NB*NM*NCH
#define OFF_YI    (OFF_YR + BMC)
#define OFF_PART  (OFF_YI + BMC)   // NS*BMC (real) then NS*BMC (imag)

__device__ __forceinline__ float sigf(float x){ return 1.0f/(1.0f+expf(-x)); }
__device__ __forceinline__ float softplusf(float x){ return (x>20.0f)? x : log1pf(expf(x)); }
__device__ __forceinline__ u16 f2bf(float f){       // RNE f32->bf16 (finite inputs)
  unsigned u = __float_as_uint(f);
  u += 0x7fffu + ((u>>16)&1u);
  return (u16)(u>>16);
}
__device__ __forceinline__ float bf2f(u16 h){ return __uint_as_float(((unsigned)h)<<16); }

// ---------------------------------------------------------------- fused prep
__global__ void k_prep(const float* __restrict__ kraw, const float* __restrict__ gom,
                       const float* __restrict__ glow, const float* __restrict__ gmid,
                       const float* __restrict__ ghigh,
                       const float* __restrict__ temb,
                       const float* __restrict__ w1, const float* __restrict__ b1,
                       const float* __restrict__ w2, const float* __restrict__ b2,
                       const float* __restrict__ tprojw, const float* __restrict__ tprojb,
                       const float* __restrict__ tau0p, const float* __restrict__ tau1p,
                       const float* __restrict__ alphap,
                       float* __restrict__ ws){
  const int b = blockIdx.x;
  const int t = threadIdx.x;
  __shared__ float sp[NKF], kpos[NKF], th_s[2];
  __shared__ float te[NTEMB], ste[NTEMB], hid[NHID], red[64];
  __shared__ float tau_sh;

  if(t<NKF) sp[t] = softplusf(kraw[t]);
  {
    float v = temb[(size_t)b*NTEMB + t];   // blockDim == 256 == NTEMB
    te[t] = v;
    ste[t] = v * sigf(v);
  }
  __syncthreads();
  // sorted |kappa| interleaving: q=0.4 -> 0.6*kpos[50]+0.4*kpos[51];
  //                              q=0.8 -> 0.2*kpos[101]+0.8*kpos[102]
  if(t==0){
    float acc = 0.0f;
    for(int k=0;k<NKF;k++){ acc += sp[k]; kpos[k]=acc; }
    th_s[0] = 0.6f*kpos[50]  + 0.4f*kpos[51];
    th_s[1] = 0.2f*kpos[101] + 0.8f*kpos[102];
  }
  if(t<NHID){
    float acc = b1[t];
    const float4* w4 = (const float4*)(w1 + (size_t)t*NTEMB);
    for(int k=0;k<NTEMB/4;k++){
      float4 wv = w4[k];
      acc = fmaf(te[4*k  ], wv.x, acc);
      acc = fmaf(te[4*k+1], wv.y, acc);
      acc = fmaf(te[4*k+2], wv.z, acc);
      acc = fmaf(te[4*k+3], wv.w, acc);
    }
    hid[t] = acc * sigf(acc);
  }
  __syncthreads();
  if(t<64) red[t] = hid[t]*w2[t] + hid[t+64]*w2[t+64];
  __syncthreads();
  if(t==0){
    float s = 0.0f;
    for(int i=0;i<64;i++) s += red[i];
    float st = tanhf(s + b2[0]);
    tau_sh = tau0p[0] + softplusf(tau1p[0])*st;
  }
  __syncthreads();
  const float th1 = th_s[0], th2 = th_s[1];
  const float alpha = softplusf(alphap[0]) + 1e-12f;
  const float tau = tau_sh;
  const float gl = sigf(glow[0]), gm = sigf(gmid[0]), gh = sigf(ghigh[0]);
  for(int m=t; m<NM; m+=256){
    float kap = (m<NKF) ? -kpos[NKF-1-m] : ((m==NKF) ? 0.0f : kpos[m-NKF-1]);
    float ka = fabsf(kap);
    float band = (ka<=th1) ? gl : ((ka<=th2) ? gm : gh);
    ws[OFF_GATE + b*NM + m] = band * sigf(alpha*(tau-ka));
    if(b==0){
      ws[OFF_KAPPA+m] = kap;
      ws[OFF_BAND +m] = band;
      ws[OFF_OMEGA+m] = fmaxf(softplusf(gom[m]), 1e-6f);
    }
  }
  if(t<NCH){
    float acc = tprojb[t];
    const float4* w4 = (const float4*)(tprojw + (size_t)t*NTEMB);
    for(int k=0;k<NTEMB/4;k++){
      float4 wv = w4[k];
      acc = fmaf(ste[4*k  ], wv.x, acc);
      acc = fmaf(ste[4*k+1], wv.y, acc);
      acc = fmaf(ste[4*k+2], wv.z, acc);
      acc = fmaf(ste[4*k+3], wv.w, acc);
    }
    ws[OFF_TCOND + b*NCH + t] = acc;
  }
}

// ---------------------------------------------------------------- analysis (MFMA)
// grid (ANMT=5, NS, NB); block 256 = 4 waves; NS=16 -> 1280 blocks = 5/CU exact.
// D[m,c] = sum_n basis[m,n] * x[c,n]; A = basis (gen in-register, per-lane
// fragment layout: row m = lane&15, k = (lane>>4)*8+j), B = x bf16 hi/lo from
// LDS (col c = lane&15, same k). 3-product bf16 split ~ fp32 accuracy.
// D layout (m89): col c = lane&15, row m = (lane>>4)*4 + reg.
__global__ __launch_bounds__(256, 4)
void k_analysis(const float* __restrict__ xf, const float* __restrict__ z,
                const float* __restrict__ gaborc,
                float* __restrict__ ws, int nsegLen){
  __shared__ u16 xhi[NCH][40], xlo[NCH][40];   // [c][n] bf16 split, 80B rows (16B-aligned)
  __shared__ float zs[ANCK];
  __shared__ float kapA[AMT], gcA[AMT], iomA[AMT];

  const int t = threadIdx.x;
  const int b = blockIdx.z, mt = blockIdx.x, ns = blockIdx.y;
  const int m0 = mt*AMT;

  if(t<AMT){
    int mg = min(m0+t, NM-1);                 // tail m>=257: junk basis, write-masked
    kapA[t] = ws[OFF_KAPPA+mg];
    gcA[t]  = gaborc[mg];
    iomA[t] = 1.0f/ws[OFF_OMEGA+mg];
  }
  __syncthreads();

  const int w  = t>>6;                        // wave id -> m16-subtile
  const int l  = t&63;
  const int lc = l&15;
  const int kb = (l>>4)*8;                    // k-base within 32-chunk
  const float mkap = kapA[w*16+lc], mgc = gcA[w*16+lc], miom = iomA[w*16+lc];

  // staging role: thread -> (channel, 8 consecutive n)
  const int cst = t>>2;
  const int j0  = (t&3)*8;
  const float tc = ws[OFF_TCOND + b*NCH + cst];

  f32x4 accR[4] = {{0,0,0,0},{0,0,0,0},{0,0,0,0},{0,0,0,0}};
  f32x4 accI[4] = {{0,0,0,0},{0,0,0,0},{0,0,0,0},{0,0,0,0}};

  const int nbase0 = ns*nsegLen;
  const float* xrow = xf + ((size_t)b*NCH + cst)*NPTS;

  for(int nb2 = nbase0; nb2 < nbase0+nsegLen; nb2 += ANCK){
    __syncthreads();                          // prev chunk LDS reads done
    if(t<ANCK) zs[t] = z[(size_t)b*NPTS + nb2 + t];
    {
      float4 v0 = *(const float4*)(xrow + nb2 + j0);
      float4 v1 = *(const float4*)(xrow + nb2 + j0 + 4);
      float vals[8] = {v0.x+tc, v0.y+tc, v0.z+tc, v0.w+tc,
                       v1.x+tc, v1.y+tc, v1.z+tc, v1.w+tc};
      bf16x8 ph, pl;
      #pragma unroll
      for(int i=0;i<8;i++){
        u16 h = f2bf(vals[i]);
        ph[i] = (short)h;
        pl[i] = (short)f2bf(vals[i] - bf2f(h));
      }
      *(bf16x8*)&xhi[cst][j0] = ph;
      *(bf16x8*)&xlo[cst][j0] = pl;
    }
    __syncthreads();                          // zs + x staged

    // A-fragments: basis generated in-register (once per (m,n) per block)
    bf16x8 cwh, cwl, swh, swl;
    #pragma unroll
    for(int j=0;j<8;j++){
      float zv = zs[kb + j];
      float th = zv*mkap;
      float sv = __sinf(th);
      float cv = __cosf(th);
      float e  = fmaf(zv, INV_PI, -mgc)*miom;
      float wv = __expf(-0.5f*e*e);
      float cwf = cv*wv, swf = sv*wv;
      u16 ch = f2bf(cwf);
      cwh[j] = (short)ch; cwl[j] = (short)f2bf(cwf - bf2f(ch));
      u16 sh = f2bf(swf);
      swh[j] = (short)sh; swl[j] = (short)f2bf(swf - bf2f(sh));
    }

    #pragma unroll
    for(int cs=0; cs<4; cs++){
      bf16x8 bh = *(const bf16x8*)&xhi[cs*16 + lc][kb];
      bf16x8 bl = *(const bf16x8*)&xlo[cs*16 + lc][kb];
      accR[cs] = __builtin_amdgcn_mfma_f32_16x16x32_bf16(cwh, bh, accR[cs], 0,0,0);
      accR[cs] = __builtin_amdgcn_mfma_f32_16x16x32_bf16(cwl, bh, accR[cs], 0,0,0);
      accR[cs] = __builtin_amdgcn_mfma_f32_16x16x32_bf16(cwh, bl, accR[cs], 0,0,0);
      accI[cs] = __builtin_amdgcn_mfma_f32_16x16x32_bf16(swh, bh, accI[cs], 0,0,0);
      accI[cs] = __builtin_amdgcn_mfma_f32_16x16x32_bf16(swl, bh, accI[cs], 0,0,0);
      accI[cs] = __builtin_amdgcn_mfma_f32_16x16x32_bf16(swh, bl, accI[cs], 0,0,0);
    }
  }

  const int NSg = gridDim.y;
  float* pr = ws + OFF_PART + (size_t)(ns*NB + b)*NM*NCH;
  float* pi = pr + (size_t)NSg*BMC;
  #pragma unroll
  for(int cs=0; cs<4; cs++){
    #pragma unroll
    for(int r=0;r<4;r++){
      int m_out = m0 + w*16 + (l>>4)*4 + r;   // D row
      int c_out = cs*16 + lc;                 // D col
      if(m_out < NM){
        pr[(size_t)m_out*NCH + c_out] = accR[cs][r];
        pi[(size_t)m_out*NCH + c_out] = accI[cs][r];
      }
    }
  }
}

// ---------------------------------------------------------------- reduce + gate + spectral multiply
__global__ void k_reduce_mult(const float* __restrict__ wr, const float* __restrict__ wi,
                              float* __restrict__ ws, int NS){
  int idx = blockIdx.x*256 + threadIdx.x;
  if(idx >= BMC) return;
  int c = idx & 63;
  int m = (idx >> 6) % NM;
  int b = idx / (NM*NCH);
  const float* part = ws + OFF_PART;
  size_t ph = (size_t)NS*BMC;
  float sr=0.0f, si=0.0f;
  for(int s=0;s<NS;s++){
    size_t o = ((size_t)(s*NB + b)*NM + m)*NCH + c;
    sr += part[o];
    si += part[o+ph];
  }
  float g  = ws[OFF_GATE + b*NM + m] * (1.0f/(float)NPTS);
  float Xr =  g*sr;
  float Xi = -g*si;
  float wrv = wr[(size_t)c*NM+m], wiv = wi[(size_t)c*NM+m];
  ws[OFF_YR + idx] =   Xr*wrv - Xi*wiv;
  ws[OFF_YI + idx] = -(Xr*wiv + Xi*wrv);    // pre-negated: synthesis is pure +FMA
}

// ---------------------------------------------------------------- synthesis V2 (unchanged)
__global__ __launch_bounds__(256, 4)
void k_synth(const float* __restrict__ z, const float* __restrict__ gaborc,
             const float* __restrict__ bias, const float* __restrict__ ws,
             float* __restrict__ out){
  __shared__ float yrs[SMT][64], yis[SMT][64];     // [m][c]
  __shared__ float cws[SMT][68], sws[SMT][68];     // [m][n] (+pad)
  __shared__ float kapF[260], gcF[260], iomF[260]; // full-range tables
  __shared__ float zs[SNCK];

  const int t = threadIdx.x;
  const int b = blockIdx.y;
  const int nb = blockIdx.x*SNCK;
  const int c0 = (t>>4)<<2;        // 4c
  const int n0 = (t&15)<<2;        // 4n

  for(int i=t; i<NM; i+=256){
    kapF[i] = ws[OFF_KAPPA+i];
    gcF[i]  = gaborc[i];
    iomF[i] = 1.0f/ws[OFF_OMEGA+i];
  }
  if(t<SNCK) zs[t] = z[(size_t)b*NPTS + nb + t];

  const float* yrBase = ws + OFF_YR + (size_t)b*NM*NCH;
  const float* yiBase = ws + OFF_YI + (size_t)b*NM*NCH;

  float4 pyr[2], pyi[2];
  #pragma unroll
  for(int e=0;e<2;e++){
    int s = t + e*256;
    pyr[e] = *(const float4*)(yrBase + (size_t)s*4);
    pyi[e] = *(const float4*)(yiBase + (size_t)s*4);
  }

  v2f acc[4][2] = {};

  for(int tile=0; tile<NTILE; tile++){
    const int mcb = tile*SMT;
    __syncthreads();
    #pragma unroll
    for(int e=0;e<2;e++){
      int s = t + e*256;
      int m = s>>4, cc = (s&15)<<2;
      *(float4*)&yrs[m][cc] = pyr[e];
      *(float4*)&yis[m][cc] = pyi[e];
    }
    {
      int n = t&63, mm = t>>6;
      float zv = zs[n], zp = zv*INV_PI;
      #pragma unroll
      for(int j=0;j<8;j++){
        int m = mm + 4*j;
        int mg = min(mcb+m, NM-1);
        float th = zv*kapF[mg];
        float sv = __sinf(th);
        float cv = __cosf(th);
        float e2 = (zp - gcF[mg])*iomF[mg];
        float w = __expf(-0.5f*e2*e2);
        cws[m][n] = cv*w;
        sws[m][n] = sv*w;
      }
    }
    __syncthreads();
    if(tile+1 < NTILE){
      const int mb2 = (tile+1)*SMT;
      #pragma unroll
      for(int e=0;e<2;e++){
        int s = t + e*256;
        int mglob = mb2 + (s>>4);
        if(mglob < NM){
          size_t o = (size_t)mb2*NCH + (size_t)s*4;
          pyr[e] = *(const float4*)(yrBase + o);
          pyi[e] = *(const float4*)(yiBase + o);
        } else {
          pyr[e] = make_float4(0,0,0,0);
          pyi[e] = make_float4(0,0,0,0);
        }
      }
    }
    #pragma unroll 4
    for(int m=0;m<SMT;m++){
      float4 yr4 = *(const float4*)&yrs[m][c0];
      float4 yi4 = *(const float4*)&yis[m][c0];
      v2f cA = *(const v2f*)&cws[m][n0];
      v2f cB = *(const v2f*)&cws[m][n0+2];
      v2f sA = *(const v2f*)&sws[m][n0];
      v2f sB = *(const v2f*)&sws[m][n0+2];
      float yrv[4]={yr4.x,yr4.y,yr4.z,yr4.w};
      float yiv[4]={yi4.x,yi4.y,yi4.z,yi4.w};
      #pragma unroll
      for(int a=0;a<4;a++){
        v2f yr = {yrv[a],yrv[a]};
        v2f yi = {yiv[a],yiv[a]};
        acc[a][0] = __builtin_elementwise_fma(yr, cA, acc[a][0]);
        acc[a][0] = __builtin_elementwise_fma(yi, sA, acc[a][0]);
        acc[a][1] = __builtin_elementwise_fma(yr, cB, acc[a][1]);
        acc[a][1] = __builtin_elementwise_fma(yi, sB, acc[a][1]);
      }
    }
  }
  #pragma unroll
  for(int a=0;a<4;a++){
    int c = c0 + a;
    float bv = bias[c];
    float4 v;
    v.x = acc[a][0][0]+bv; v.y = acc[a][0][1]+bv;
    v.z = acc[a][1][0]+bv; v.w = acc[a][1][1]+bv;
    *(float4*)(out + ((size_t)b*NCH + c)*NPTS + nb + n0) = v;
  }
}

// ---------------------------------------------------------------- launch
extern "C" void kernel_launch(void* const* d_in, const int* in_sizes, int n_in,
                              void* d_out, int out_size, void* d_ws, size_t ws_size,
                              hipStream_t stream){
  const float* x_feat = (const float*)d_in[0];
  const float* z      = (const float*)d_in[1];
  const float* temb   = (const float*)d_in[2];
  const float* kraw   = (const float*)d_in[3];
  const float* gaborc = (const float*)d_in[4];
  const float* gom    = (const float*)d_in[5];
  const float* wr     = (const float*)d_in[6];
  const float* wi     = (const float*)d_in[7];
  const float* bias   = (const float*)d_in[8];
  const float* tprojw = (const float*)d_in[9];
  const float* tprojb = (const float*)d_in[10];
  const float* w1     = (const float*)d_in[11];
  const float* b1     = (const float*)d_in[12];
  const float* w2     = (const float*)d_in[13];
  const float* b2     = (const float*)d_in[14];
  const float* tau0   = (const float*)d_in[15];
  const float* tau1   = (const float*)d_in[16];
  const float* alphar = (const float*)d_in[17];
  const float* glow   = (const float*)d_in[18];
  const float* gmid   = (const float*)d_in[19];
  const float* ghigh  = (const float*)d_in[20];
  float* out = (float*)d_out;
  float* ws  = (float*)d_ws;

  // NS=16 -> analysis grid 5*16*16 = 1280 blocks = 5.0/CU exact.
  // Pure function of ws_size (capture-safe).
  int NS = 16;
  while(NS > 1 && ws_size < (size_t)(OFF_PART + 2*(size_t)NS*BMC)*sizeof(float)) NS >>= 1;

  k_prep      <<<NB, 256, 0, stream>>>(kraw, gom, glow, gmid, ghigh, temb,
                                       w1, b1, w2, b2, tprojw, tprojb,
                                       tau0, tau1, alphar, ws);
  k_analysis  <<<dim3(ANMT, NS, NB), 256, 0, stream>>>(x_feat, z, gaborc, ws, NPTS/NS);
  k_reduce_mult<<<(BMC+255)/256, 256, 0, stream>>>(wr, wi, ws, NS);
  k_synth     <<<dim3(NPTS/SNCK, NB), 256, 0, stream>>>(z, gaborc, bias, ws, out);
}